// Round 6
// baseline (162.164 us; speedup 1.0000x reference)
//
#include <hip/hip_runtime.h>
#include <hip/hip_bf16.h>

#define D_DIM 1024
#define S_DIM 2048
#define B_DIM 4
#define KTAPS 16

typedef short bf16x8 __attribute__((ext_vector_type(8)));
typedef float f32x4 __attribute__((ext_vector_type(4)));

// async global->LDS, 16B per lane (global_load_lds_dwordx4)
#define GLOAD16(gptr, lptr) \
  __builtin_amdgcn_global_load_lds((const __attribute__((address_space(1))) unsigned int*)(gptr), \
                                   (__attribute__((address_space(3))) unsigned int*)(lptr), 16, 0, 0)

// s_waitcnt immediates (gfx9 encoding: vm[3:0]=b0-3, exp=b4-6, lgkm=b8-11, vm[5:4]=b14-15)
#define WAIT_VM0   0x0F70   // vmcnt(0), lgkm/exp no-wait
#define WAIT_LGKM0 0xC07F   // lgkmcnt(0), vm/exp no-wait

static __device__ __forceinline__ short f2bs(float f) {
  __hip_bfloat16 h = __float2bfloat16(f);
  return *reinterpret_cast<short*>(&h);
}
static __device__ __forceinline__ float bs2f(short s) {
  unsigned int u = ((unsigned int)(unsigned short)s) << 16;
  return __builtin_bit_cast(float, u);
}

// ---------------------------------------------------------------------------
// Kernel 1 (merged setup): blocks [0,4096) cast W_out to bf16; blocks
// [4096,4160) compute impulse response g_k[d] = C_d . A_d^k . B_d
// (Dm folded into tap 0).
// ---------------------------------------------------------------------------
__global__ void setup_kernel(const float* __restrict__ W, __hip_bfloat16* __restrict__ Wb,
                             const float* __restrict__ A, const float* __restrict__ Bm,
                             const float* __restrict__ Cm, const float* __restrict__ Dm,
                             float* __restrict__ gT) {
  if (blockIdx.x < 4096) {
    int i = blockIdx.x * 256 + threadIdx.x;
    Wb[i] = __float2bfloat16(W[i]);
    return;
  }
  const int gb   = blockIdx.x - 4096;  // 0..63
  const int wid  = threadIdx.x >> 6;   // 0..3
  const int lane = threadIdx.x & 63;
  const int sub  = lane >> 4;          // 0..3 (channel within wave)
  const int n    = lane & 15;          // state index
  const int d    = gb * 16 + wid * 4 + sub;
  float Ar[16];
#pragma unroll
  for (int m = 0; m < 16; ++m) Ar[m] = A[d * 256 + n * 16 + m];
  float v = Bm[d * 16 + n];
  const float c   = Cm[d * 16 + n];
  const float dmv = Dm[d];
  const int base  = sub << 4;
  for (int k = 0; k < KTAPS; ++k) {
    float dot = c * v;
    dot += __shfl_xor(dot, 1);
    dot += __shfl_xor(dot, 2);
    dot += __shfl_xor(dot, 4);
    dot += __shfl_xor(dot, 8);
    if (k == 0) dot += dmv;            // fold the D x_t skip term into tap 0
    if (n == 0) gT[k * D_DIM + d] = dot;
    float nv = 0.f;
#pragma unroll
    for (int m = 0; m < 16; ++m) nv = fmaf(Ar[m], __shfl(v, base + m), nv);
    v = nv;
  }
}

// ---------------------------------------------------------------------------
// Kernel 2: depthwise causal conv, 16 taps, y emitted in bf16. Block =
// (b, 64-row chunk, 256-channel group), 512 blocks.
// ---------------------------------------------------------------------------
__global__ __launch_bounds__(256, 4) void conv_kernel(const float* __restrict__ x,
                                                      const float* __restrict__ gT,
                                                      __hip_bfloat16* __restrict__ y) {
  const int bx    = blockIdx.x;        // 512 blocks: b(4) x chunk(32) x dg(4)
  const int b     = bx >> 7;
  const int rem   = bx & 127;
  const int chunk = rem >> 2;          // 0..31
  const int dg    = rem & 3;
  const int d     = dg * 256 + threadIdx.x;
  const int s0    = chunk * 64;
  const float* xb = x + b * (S_DIM * D_DIM) + d;
  short* yb       = (short*)y + b * (S_DIM * D_DIM) + d;

  float g[KTAPS];
#pragma unroll
  for (int k = 0; k < KTAPS; ++k) g[k] = gT[k * D_DIM + d];

  float hist[16];                      // x[s - 16 .. s - 1]
#pragma unroll
  for (int i = 0; i < 16; ++i) {
    int s = s0 - 16 + i;
    hist[i] = (s >= 0) ? xb[s * D_DIM] : 0.0f;
  }

  for (int t = 0; t < 4; ++t) {        // 4 sub-tiles of 16 outputs
    const int sb = s0 + t * 16;
    float cur[16];
#pragma unroll
    for (int i = 0; i < 16; ++i) cur[i] = xb[(sb + i) * D_DIM];
#pragma unroll
    for (int j = 0; j < 16; ++j) {
      float acc = 0.f;
#pragma unroll
      for (int k = 0; k < KTAPS; ++k) {
        const int idx = j - k;          // compile-time constant
        const float xv = (idx >= 0) ? cur[idx] : hist[16 + idx];
        acc = fmaf(g[k], xv, acc);
      }
      yb[(sb + j) * D_DIM] = f2bs(acc);
    }
#pragma unroll
    for (int i = 0; i < 16; ++i) hist[i] = cur[i];
  }
}

// ---------------------------------------------------------------------------
// Kernel 3: LayerNorm(D=1024) + exact GELU, bf16 in -> bf16 out. Block per
// row; thread handles 4 contiguous channels.
// ---------------------------------------------------------------------------
__global__ __launch_bounds__(256) void ln_gelu_kernel(const __hip_bfloat16* __restrict__ y,
                                                      const float* __restrict__ w,
                                                      const float* __restrict__ bsh,
                                                      __hip_bfloat16* __restrict__ act) {
  __shared__ float red0[4];
  __shared__ float red1[4];
  const int row = blockIdx.x;
  const int tid = threadIdx.x;
  const int lane = tid & 63, wid = tid >> 6;
  const int d0 = tid * 4;

  const short4 s4 = *(const short4*)((const short*)y + (size_t)row * D_DIM + d0);
  float v[4] = {bs2f(s4.x), bs2f(s4.y), bs2f(s4.z), bs2f(s4.w)};

  float s = v[0] + v[1] + v[2] + v[3];
  s += __shfl_xor(s, 1);  s += __shfl_xor(s, 2);  s += __shfl_xor(s, 4);
  s += __shfl_xor(s, 8);  s += __shfl_xor(s, 16); s += __shfl_xor(s, 32);
  if (lane == 0) red0[wid] = s;
  __syncthreads();
  const float mu = (red0[0] + red0[1] + red0[2] + red0[3]) * (1.0f / D_DIM);

  float sq = 0.f;
#pragma unroll
  for (int j = 0; j < 4; ++j) { float t = v[j] - mu; sq = fmaf(t, t, sq); }
  sq += __shfl_xor(sq, 1);  sq += __shfl_xor(sq, 2);  sq += __shfl_xor(sq, 4);
  sq += __shfl_xor(sq, 8);  sq += __shfl_xor(sq, 16); sq += __shfl_xor(sq, 32);
  if (lane == 0) red1[wid] = sq;
  __syncthreads();
  const float var = (red1[0] + red1[1] + red1[2] + red1[3]) * (1.0f / D_DIM);
  const float inv = rsqrtf(var + 1e-5f);

  const float4 w4 = *(const float4*)&w[d0];
  const float4 b4 = *(const float4*)&bsh[d0];
  const float wv[4] = {w4.x, w4.y, w4.z, w4.w};
  const float bv[4] = {b4.x, b4.y, b4.z, b4.w};
  short4 o;
  short* op = &o.x;
#pragma unroll
  for (int j = 0; j < 4; ++j) {
    float t = (v[j] - mu) * inv * wv[j] + bv[j];
    float ge = 0.5f * t * (1.f + erff(t * 0.70710678118654752f));  // exact gelu
    op[j] = f2bs(ge);
  }
  *(short4*)((short*)act + (size_t)row * D_DIM + d0) = o;
}

// ---------------------------------------------------------------------------
// Kernel 4: out = x + Act @ W^T + b_out.  BARRIER-FREE single-wave MFMA GEMM.
// Block = 1 wave (64 threads), tile 64x64, BK=64, single 16 KB LDS buffer.
// No __syncthreads: the wave orders its own pipeline with explicit s_waitcnt
// (vmcnt(0) after global_load_lds staging; lgkmcnt(0) before the DMA
// overwrites LDS). 2048 blocks -> ~8-10 independent wave-pipelines per CU,
// so per-wave drains overlap instead of block-wide barrier stalls.
// XOR swizzle: 16B chunk c of row r at slot c^(r&7) -> 2-way (free) reads.
// Staging: lane l -> row (l>>3), fetches global chunk (l&7)^(l>>3); GLOAD r
// covers rows r*8..r*8+7 at LDS base + r*1KB (wave-uniform + lane*16).
// A-frag: lane holds Act[m = l16][kk + kq*8 + j], C/D: col=l16, row=kq*4+reg.
// ---------------------------------------------------------------------------
__global__ __launch_bounds__(64, 2) void gemm_kernel(const __hip_bfloat16* __restrict__ Act,
                                                     const __hip_bfloat16* __restrict__ Wb,
                                                     const float* __restrict__ x,
                                                     const float* __restrict__ bout,
                                                     float* __restrict__ out) {
  __shared__ short Al[64 * 64];   // 8 KB
  __shared__ short Bl[64 * 64];   // 8 KB
  const int lane = threadIdx.x;
  const int mBase = blockIdx.x * 64;
  const int nBase = blockIdx.y * 64;
  const int l16 = lane & 15;
  const int kq  = lane >> 4;      // 0..3

  // staging address: row = lane>>3, swizzled chunk = (lane&7)^(lane>>3)
  const int srow = lane >> 3;
  const int cg   = (lane & 7) ^ srow;
  const short* Agl = (const short*)Act + (size_t)(mBase + srow) * D_DIM + (cg << 3);
  const short* Bgl = (const short*)Wb  + (size_t)(nBase + srow) * D_DIM + (cg << 3);

  f32x4 acc[4][4];
#pragma unroll
  for (int mt = 0; mt < 4; ++mt)
#pragma unroll
    for (int nt = 0; nt < 4; ++nt) acc[mt][nt] = (f32x4){0.f, 0.f, 0.f, 0.f};

  for (int it = 0; it < 16; ++it) {
    const int k0 = it * 64;
#pragma unroll
    for (int r = 0; r < 8; ++r) {       // 8 rows per GLOAD round (1 KB each)
      GLOAD16(Agl + r * 8 * D_DIM + k0, Al + r * 512);
      GLOAD16(Bgl + r * 8 * D_DIM + k0, Bl + r * 512);
    }
    __builtin_amdgcn_s_waitcnt(WAIT_VM0);    // staged tile visible to this wave
#pragma unroll
    for (int kk = 0; kk < 64; kk += 32) {
      bf16x8 af[4], bfr[4];
      const int cgr = (kk >> 3) + kq;        // global chunk this fragment needs
#pragma unroll
      for (int mt = 0; mt < 4; ++mt) {
        const int r = mt * 16 + l16;
        af[mt] = *(const bf16x8*)&Al[r * 64 + ((cgr ^ (r & 7)) << 3)];
      }
#pragma unroll
      for (int nt = 0; nt < 4; ++nt) {
        const int r = nt * 16 + l16;
        bfr[nt] = *(const bf16x8*)&Bl[r * 64 + ((cgr ^ (r & 7)) << 3)];
      }
#pragma unroll
      for (int mt = 0; mt < 4; ++mt)
#pragma unroll
        for (int nt = 0; nt < 4; ++nt)
          acc[mt][nt] = __builtin_amdgcn_mfma_f32_16x16x32_bf16(af[mt], bfr[nt], acc[mt][nt], 0, 0, 0);
    }
    __builtin_amdgcn_s_waitcnt(WAIT_LGKM0);  // reads retired before DMA overwrite
  }

  const int r0 = kq * 4;
#pragma unroll
  for (int mt = 0; mt < 4; ++mt) {
    const int row = mBase + mt * 16 + r0;
#pragma unroll
    for (int nt = 0; nt < 4; ++nt) {
      const int col = nBase + nt * 16 + l16;
      const float bo = bout[col];
#pragma unroll
      for (int r = 0; r < 4; ++r) {
        const int idx = (row + r) * D_DIM + col;
        out[idx] = x[idx] + acc[mt][nt][r] + bo;
      }
    }
  }
}

// ---------------------------------------------------------------------------
extern "C" void kernel_launch(void* const* d_in, const int* in_sizes, int n_in,
                              void* d_out, int out_size, void* d_ws, size_t ws_size,
                              hipStream_t stream) {
  const float* x    = (const float*)d_in[0];
  const float* A    = (const float*)d_in[1];
  const float* Bm   = (const float*)d_in[2];
  const float* Cm   = (const float*)d_in[3];
  const float* Dm   = (const float*)d_in[4];
  const float* lnw  = (const float*)d_in[5];
  const float* lnb  = (const float*)d_in[6];
  const float* Wout = (const float*)d_in[7];
  const float* bout = (const float*)d_in[8];
  float* out = (float*)d_out;

  char* ws = (char*)d_ws;
  float* gT            = (float*)ws;                        // 16*1024*4   = 64 KB
  __hip_bfloat16* Wb   = (__hip_bfloat16*)(ws + 262144);    // 1024*1024*2 = 2 MB
  __hip_bfloat16* Act  = (__hip_bfloat16*)(ws + 2359296);   // 8192*1024*2 = 16.75 MB
  __hip_bfloat16* ybf  = (__hip_bfloat16*)(ws + 19136512);  // 8192*1024*2 = 16.75 MB

  setup_kernel<<<4160, 256, 0, stream>>>(Wout, Wb, A, Bm, Cm, Dm, gT);
  conv_kernel<<<512, 256, 0, stream>>>(x, gT, ybf);
  ln_gelu_kernel<<<8192, 256, 0, stream>>>(ybf, lnw, lnb, Act);
  gemm_kernel<<<dim3(128, 16), 64, 0, stream>>>(Act, Wb, x, bout, out);
}

// Round 7
// 160.356 us; speedup vs baseline: 1.0113x; 1.0113x over previous
//
#include <hip/hip_runtime.h>
#include <hip/hip_bf16.h>

#define D_DIM 1024
#define S_DIM 2048
#define B_DIM 4
#define KTAPS 16

typedef short bf16x8 __attribute__((ext_vector_type(8)));
typedef float f32x4 __attribute__((ext_vector_type(4)));

// async global->LDS, 16B per lane (global_load_lds_dwordx4)
#define GLOAD16(gptr, lptr) \
  __builtin_amdgcn_global_load_lds((const __attribute__((address_space(1))) unsigned int*)(gptr), \
                                   (__attribute__((address_space(3))) unsigned int*)(lptr), 16, 0, 0)

// s_waitcnt immediates (gfx9: vm[3:0]=b0-3, exp=b4-6, lgkm=b8-11, vm[5:4]=b14-15)
#define WAIT_VM0 0x0F70   // vmcnt(0), lgkm/exp no-wait

static __device__ __forceinline__ short f2bs(float f) {
  __hip_bfloat16 h = __float2bfloat16(f);
  return *reinterpret_cast<short*>(&h);
}
static __device__ __forceinline__ float bs2f(short s) {
  unsigned int u = ((unsigned int)(unsigned short)s) << 16;
  return __builtin_bit_cast(float, u);
}

// ---------------------------------------------------------------------------
// Kernel 1 (merged setup): blocks [0,4096) cast W_out to bf16; blocks
// [4096,4160) compute impulse response g_k[d] = C_d . A_d^k . B_d
// (Dm folded into tap 0).
// ---------------------------------------------------------------------------
__global__ void setup_kernel(const float* __restrict__ W, __hip_bfloat16* __restrict__ Wb,
                             const float* __restrict__ A, const float* __restrict__ Bm,
                             const float* __restrict__ Cm, const float* __restrict__ Dm,
                             float* __restrict__ gT) {
  if (blockIdx.x < 4096) {
    int i = blockIdx.x * 256 + threadIdx.x;
    Wb[i] = __float2bfloat16(W[i]);
    return;
  }
  const int gb   = blockIdx.x - 4096;  // 0..63
  const int wid  = threadIdx.x >> 6;   // 0..3
  const int lane = threadIdx.x & 63;
  const int sub  = lane >> 4;          // 0..3 (channel within wave)
  const int n    = lane & 15;          // state index
  const int d    = gb * 16 + wid * 4 + sub;
  float Ar[16];
#pragma unroll
  for (int m = 0; m < 16; ++m) Ar[m] = A[d * 256 + n * 16 + m];
  float v = Bm[d * 16 + n];
  const float c   = Cm[d * 16 + n];
  const float dmv = Dm[d];
  const int base  = sub << 4;
  for (int k = 0; k < KTAPS; ++k) {
    float dot = c * v;
    dot += __shfl_xor(dot, 1);
    dot += __shfl_xor(dot, 2);
    dot += __shfl_xor(dot, 4);
    dot += __shfl_xor(dot, 8);
    if (k == 0) dot += dmv;            // fold the D x_t skip term into tap 0
    if (n == 0) gT[k * D_DIM + d] = dot;
    float nv = 0.f;
#pragma unroll
    for (int m = 0; m < 16; ++m) nv = fmaf(Ar[m], __shfl(v, base + m), nv);
    v = nv;
  }
}

// ---------------------------------------------------------------------------
// Kernel 2: depthwise causal conv, 16 taps, y emitted in bf16. Block =
// (b, 64-row chunk, 256-channel group), 512 blocks.
// ---------------------------------------------------------------------------
__global__ __launch_bounds__(256, 4) void conv_kernel(const float* __restrict__ x,
                                                      const float* __restrict__ gT,
                                                      __hip_bfloat16* __restrict__ y) {
  const int bx    = blockIdx.x;        // 512 blocks: b(4) x chunk(32) x dg(4)
  const int b     = bx >> 7;
  const int rem   = bx & 127;
  const int chunk = rem >> 2;          // 0..31
  const int dg    = rem & 3;
  const int d     = dg * 256 + threadIdx.x;
  const int s0    = chunk * 64;
  const float* xb = x + b * (S_DIM * D_DIM) + d;
  short* yb       = (short*)y + b * (S_DIM * D_DIM) + d;

  float g[KTAPS];
#pragma unroll
  for (int k = 0; k < KTAPS; ++k) g[k] = gT[k * D_DIM + d];

  float hist[16];                      // x[s - 16 .. s - 1]
#pragma unroll
  for (int i = 0; i < 16; ++i) {
    int s = s0 - 16 + i;
    hist[i] = (s >= 0) ? xb[s * D_DIM] : 0.0f;
  }

  for (int t = 0; t < 4; ++t) {        // 4 sub-tiles of 16 outputs
    const int sb = s0 + t * 16;
    float cur[16];
#pragma unroll
    for (int i = 0; i < 16; ++i) cur[i] = xb[(sb + i) * D_DIM];
#pragma unroll
    for (int j = 0; j < 16; ++j) {
      float acc = 0.f;
#pragma unroll
      for (int k = 0; k < KTAPS; ++k) {
        const int idx = j - k;          // compile-time constant
        const float xv = (idx >= 0) ? cur[idx] : hist[16 + idx];
        acc = fmaf(g[k], xv, acc);
      }
      yb[(sb + j) * D_DIM] = f2bs(acc);
    }
#pragma unroll
    for (int i = 0; i < 16; ++i) hist[i] = cur[i];
  }
}

// ---------------------------------------------------------------------------
// Kernel 3: LayerNorm(D=1024) + exact GELU, bf16 in -> bf16 out. Block per
// row; thread handles 4 contiguous channels.
// ---------------------------------------------------------------------------
__global__ __launch_bounds__(256) void ln_gelu_kernel(const __hip_bfloat16* __restrict__ y,
                                                      const float* __restrict__ w,
                                                      const float* __restrict__ bsh,
                                                      __hip_bfloat16* __restrict__ act) {
  __shared__ float red0[4];
  __shared__ float red1[4];
  const int row = blockIdx.x;
  const int tid = threadIdx.x;
  const int lane = tid & 63, wid = tid >> 6;
  const int d0 = tid * 4;

  const short4 s4 = *(const short4*)((const short*)y + (size_t)row * D_DIM + d0);
  float v[4] = {bs2f(s4.x), bs2f(s4.y), bs2f(s4.z), bs2f(s4.w)};

  float s = v[0] + v[1] + v[2] + v[3];
  s += __shfl_xor(s, 1);  s += __shfl_xor(s, 2);  s += __shfl_xor(s, 4);
  s += __shfl_xor(s, 8);  s += __shfl_xor(s, 16); s += __shfl_xor(s, 32);
  if (lane == 0) red0[wid] = s;
  __syncthreads();
  const float mu = (red0[0] + red0[1] + red0[2] + red0[3]) * (1.0f / D_DIM);

  float sq = 0.f;
#pragma unroll
  for (int j = 0; j < 4; ++j) { float t = v[j] - mu; sq = fmaf(t, t, sq); }
  sq += __shfl_xor(sq, 1);  sq += __shfl_xor(sq, 2);  sq += __shfl_xor(sq, 4);
  sq += __shfl_xor(sq, 8);  sq += __shfl_xor(sq, 16); sq += __shfl_xor(sq, 32);
  if (lane == 0) red1[wid] = sq;
  __syncthreads();
  const float var = (red1[0] + red1[1] + red1[2] + red1[3]) * (1.0f / D_DIM);
  const float inv = rsqrtf(var + 1e-5f);

  const float4 w4 = *(const float4*)&w[d0];
  const float4 b4 = *(const float4*)&bsh[d0];
  const float wv[4] = {w4.x, w4.y, w4.z, w4.w};
  const float bv[4] = {b4.x, b4.y, b4.z, b4.w};
  short4 o;
  short* op = &o.x;
#pragma unroll
  for (int j = 0; j < 4; ++j) {
    float t = (v[j] - mu) * inv * wv[j] + bv[j];
    float ge = 0.5f * t * (1.f + erff(t * 0.70710678118654752f));  // exact gelu
    op[j] = f2bs(ge);
  }
  *(short4*)((short*)act + (size_t)row * D_DIM + d0) = o;
}

// ---------------------------------------------------------------------------
// Kernel 4: out = x + Act @ W^T + b_out.  Double-buffered LDS MFMA GEMM with
// RAW s_barrier (no compiler vmcnt(0)+lgkmcnt(0) drain of __syncthreads).
// 128x128 tile, BK=64, 2 x (16+16) KB LDS. Pipeline per iteration:
//   s_waitcnt vmcnt(0)   <- waits only on cur tile's DMA, which was issued
//                           LAST iteration and overlapped with last compute
//   s_barrier            <- visibility of cur tile + WAR: all waves are past
//                           reading buf^1 before we re-issue DMA into it
//   issue DMA(buf^1, tile it+1)   <- flies during compute below
//   compute(buf[cur])    <- ds_read (XOR-swizzled, conflict-free) + 32 MFMA
// 4 waves (2x2), wave = 64x64 via 4x4 grid of 16x16x32 MFMA.
// C/D: col = lane&15, row = (lane>>4)*4 + reg.
// ---------------------------------------------------------------------------
__global__ __launch_bounds__(256, 2) void gemm_kernel(const __hip_bfloat16* __restrict__ Act,
                                                      const __hip_bfloat16* __restrict__ Wb,
                                                      const float* __restrict__ x,
                                                      const float* __restrict__ bout,
                                                      float* __restrict__ out) {
  __shared__ short Al[2][128 * 64];  // 2 x 16 KB
  __shared__ short Bl[2][128 * 64];  // 2 x 16 KB
  const int tid  = threadIdx.x;
  const int lane = tid & 63;
  const int wave = tid >> 6;
  const int mBase = blockIdx.x * 128;
  const int nBase = blockIdx.y * 128;
  const int wm = (wave & 1) * 64;
  const int wn = (wave >> 1) * 64;
  const int l16 = lane & 15;
  const int kq  = lane >> 4;          // 0..3 k-quad

  // staging: thread t -> row (tid>>3) (+32/round, 4 rounds), swizzled chunk
  const int srow = tid >> 3;                      // 0..31
  const int cg   = (tid & 7) ^ (srow & 7);        // global 16B chunk fetched
  const short* Ag = (const short*)Act + (mBase + srow) * D_DIM + cg * 8;
  const short* Bg = (const short*)Wb  + (nBase + srow) * D_DIM + cg * 8;

  f32x4 acc[4][4];
#pragma unroll
  for (int mt = 0; mt < 4; ++mt)
#pragma unroll
    for (int nt = 0; nt < 4; ++nt) acc[mt][nt] = (f32x4){0.f, 0.f, 0.f, 0.f};

  // prologue: stage tile 0 into buffer 0
#pragma unroll
  for (int r = 0; r < 4; ++r) {
    GLOAD16(Ag + r * 32 * D_DIM, &Al[0][tid * 8 + r * 2048]);
    GLOAD16(Bg + r * 32 * D_DIM, &Bl[0][tid * 8 + r * 2048]);
  }

  for (int it = 0; it < 16; ++it) {
    const int cur = it & 1;
    __builtin_amdgcn_s_waitcnt(WAIT_VM0);   // cur tile's DMA complete (overlapped)
    __builtin_amdgcn_s_barrier();           // all waves: cur visible, buf^1 free
    if (it < 15) {
      const int k1 = (it + 1) * 64;
#pragma unroll
      for (int r = 0; r < 4; ++r) {
        GLOAD16(Ag + r * 32 * D_DIM + k1, &Al[cur ^ 1][tid * 8 + r * 2048]);
        GLOAD16(Bg + r * 32 * D_DIM + k1, &Bl[cur ^ 1][tid * 8 + r * 2048]);
      }
    }
    const short* Ab = Al[cur];
    const short* Bb = Bl[cur];
#pragma unroll
    for (int kk = 0; kk < 64; kk += 32) {
      bf16x8 af[4], bfr[4];
      const int cgr = (kk >> 3) + kq;       // global chunk this fragment needs
#pragma unroll
      for (int mt = 0; mt < 4; ++mt) {
        const int r = wm + mt * 16 + l16;
        af[mt] = *(const bf16x8*)&Ab[r * 64 + ((cgr ^ (r & 7)) << 3)];
      }
#pragma unroll
      for (int nt = 0; nt < 4; ++nt) {
        const int r = wn + nt * 16 + l16;
        bfr[nt] = *(const bf16x8*)&Bb[r * 64 + ((cgr ^ (r & 7)) << 3)];
      }
#pragma unroll
      for (int mt = 0; mt < 4; ++mt)
#pragma unroll
        for (int nt = 0; nt < 4; ++nt)
          acc[mt][nt] = __builtin_amdgcn_mfma_f32_16x16x32_bf16(af[mt], bfr[nt], acc[mt][nt], 0, 0, 0);
    }
  }

  const int r0 = kq * 4;
#pragma unroll
  for (int mt = 0; mt < 4; ++mt) {
    const int row = mBase + wm + mt * 16 + r0;
#pragma unroll
    for (int nt = 0; nt < 4; ++nt) {
      const int col = nBase + wn + nt * 16 + l16;
      const float bo = bout[col];
#pragma unroll
      for (int r = 0; r < 4; ++r) {
        const int idx = (row + r) * D_DIM + col;
        out[idx] = x[idx] + acc[mt][nt][r] + bo;
      }
    }
  }
}

// ---------------------------------------------------------------------------
extern "C" void kernel_launch(void* const* d_in, const int* in_sizes, int n_in,
                              void* d_out, int out_size, void* d_ws, size_t ws_size,
                              hipStream_t stream) {
  const float* x    = (const float*)d_in[0];
  const float* A    = (const float*)d_in[1];
  const float* Bm   = (const float*)d_in[2];
  const float* Cm   = (const float*)d_in[3];
  const float* Dm   = (const float*)d_in[4];
  const float* lnw  = (const float*)d_in[5];
  const float* lnb  = (const float*)d_in[6];
  const float* Wout = (const float*)d_in[7];
  const float* bout = (const float*)d_in[8];
  float* out = (float*)d_out;

  char* ws = (char*)d_ws;
  float* gT            = (float*)ws;                        // 16*1024*4   = 64 KB
  __hip_bfloat16* Wb   = (__hip_bfloat16*)(ws + 262144);    // 1024*1024*2 = 2 MB
  __hip_bfloat16* Act  = (__hip_bfloat16*)(ws + 2359296);   // 8192*1024*2 = 16.75 MB
  __hip_bfloat16* ybf  = (__hip_bfloat16*)(ws + 19136512);  // 8192*1024*2 = 16.75 MB

  setup_kernel<<<4160, 256, 0, stream>>>(Wout, Wb, A, Bm, Cm, Dm, gT);
  conv_kernel<<<512, 256, 0, stream>>>(x, gT, ybf);
  ln_gelu_kernel<<<8192, 256, 0, stream>>>(ybf, lnw, lnb, Act);
  gemm_kernel<<<dim3(64, 8), 256, 0, stream>>>(Act, Wb, x, bout, out);
}